// Round 2
// baseline (45.484 us; speedup 1.0000x reference)
//
#include <hip/hip_runtime.h>

// Raw image moments m_pq = sum_{y,x} I[y,x] * x^p * y^q for the 10 moments
// up to order 3, output order: m00 m10 m01 m20 m11 m02 m30 m21 m12 m03.
// Input: [4096, 128, 128, 1] float32. Output: [4096, 10] float32.
//
// One block (256 threads) per image; 16 x float4 nontemporal loads per
// thread. Key fact: 256 % 32 == 0, so each thread's x-coordinates (f & 31)
// are FIXED across iterations -> precompute x-power weights once and fold
// each float4 into 4 fixed-x dot products s_p = sum_j p_j * x_j^p, then do
// 10 y-weighted accumulations (y = (tid>>5) + 8*i). ~28 VALU ops per 16 B
// load vs ~45 in the naive form.

#define IMG_ELEMS 16384   // 128*128

typedef float f4v __attribute__((ext_vector_type(4)));

__global__ __launch_bounds__(256) void RawMoments_kernel(
    const float* __restrict__ in, float* __restrict__ out)
{
    const int b = blockIdx.x;
    const f4v* img = reinterpret_cast<const f4v*>(in + (size_t)b * IMG_ELEMS);
    const int tid = threadIdx.x;

    // Fixed per-thread x coordinates (4 consecutive pixels).
    const float x0 = (float)((tid & 31) << 2);
    float xw1[4], xw2[4], xw3[4];
#pragma unroll
    for (int j = 0; j < 4; ++j) {
        const float x = x0 + (float)j;
        xw1[j] = x;
        xw2[j] = x * x;
        xw3[j] = x * x * x;
    }
    const float ybase = (float)(tid >> 5);   // y = ybase + 8*i

    float acc[10];
#pragma unroll
    for (int i = 0; i < 10; ++i) acc[i] = 0.0f;

#pragma unroll
    for (int i = 0; i < 16; ++i) {
        const f4v v = __builtin_nontemporal_load(&img[tid + i * 256]);
        const float y  = ybase + (float)(i << 3);
        const float y2 = y * y;
        const float y3 = y2 * y;
        // Fixed-x dot products over the 4 pixels.
        float s0 = v.x + v.y + v.z + v.w;
        float s1 = v.x * xw1[0] + v.y * xw1[1] + v.z * xw1[2] + v.w * xw1[3];
        float s2 = v.x * xw2[0] + v.y * xw2[1] + v.z * xw2[2] + v.w * xw2[3];
        float s3 = v.x * xw3[0] + v.y * xw3[1] + v.z * xw3[2] + v.w * xw3[3];
        acc[0] += s0;        // m00
        acc[1] += s1;        // m10
        acc[2] += s0 * y;    // m01
        acc[3] += s2;        // m20
        acc[4] += s1 * y;    // m11
        acc[5] += s0 * y2;   // m02
        acc[6] += s3;        // m30
        acc[7] += s2 * y;    // m21
        acc[8] += s1 * y2;   // m12
        acc[9] += s0 * y3;   // m03
    }

    // Intra-wave 64-lane shfl_down tree reduce.
#pragma unroll
    for (int off = 32; off > 0; off >>= 1) {
#pragma unroll
        for (int i = 0; i < 10; ++i)
            acc[i] += __shfl_down(acc[i], off, 64);
    }

    // Cross-wave reduce through LDS (4 waves x 10 floats).
    __shared__ float red[4][10];
    const int wave = tid >> 6;
    const int lane = tid & 63;
    if (lane == 0) {
#pragma unroll
        for (int i = 0; i < 10; ++i) red[wave][i] = acc[i];
    }
    __syncthreads();
    if (tid < 10) {
        const float s = red[0][tid] + red[1][tid] + red[2][tid] + red[3][tid];
        out[(size_t)b * 10 + tid] = s;
    }
}

extern "C" void kernel_launch(void* const* d_in, const int* in_sizes, int n_in,
                              void* d_out, int out_size, void* d_ws, size_t ws_size,
                              hipStream_t stream)
{
    const float* in = (const float*)d_in[0];
    float* out = (float*)d_out;
    const int n_imgs = in_sizes[0] / IMG_ELEMS;   // 4096
    RawMoments_kernel<<<n_imgs, 256, 0, stream>>>(in, out);
}

// Round 3
// 44.216 us; speedup vs baseline: 1.0287x; 1.0287x over previous
//
#include <hip/hip_runtime.h>

// Raw image moments m_pq = sum_{y,x} I[y,x] * x^p * y^q for the 10 moments
// up to order 3, output order: m00 m10 m01 m20 m11 m02 m30 m21 m12 m03.
// Input: [4096, 128, 128, 1] float32. Output: [4096, 10] float32.
//
// One block (256 threads) per image; 16 x float4 coalesced loads per thread
// (plain loads — nontemporal hint measured neutral-to-negative, R2).
// 256 % 32 == 0 so each thread's x-coords (f & 31) are fixed across
// iterations: precompute x-power weights once, fold each float4 into 4
// fixed-x dot products s_p = sum_j p_j * x_j^p, then 10 y-weighted
// accumulations (y = (tid>>5) + 8*i).
//
// Measured at the HBM read-stream roofline: 268.4 MB mandatory reads at
// ~6.0 TB/s achieved (96% of the 6.29 TB/s float4-copy ceiling) = ~44.5 us.

#define IMG_ELEMS 16384   // 128*128

typedef float f4v __attribute__((ext_vector_type(4)));

__global__ __launch_bounds__(256) void RawMoments_kernel(
    const float* __restrict__ in, float* __restrict__ out)
{
    const int b = blockIdx.x;
    const f4v* img = reinterpret_cast<const f4v*>(in + (size_t)b * IMG_ELEMS);
    const int tid = threadIdx.x;

    // Fixed per-thread x coordinates (4 consecutive pixels).
    const float x0 = (float)((tid & 31) << 2);
    float xw1[4], xw2[4], xw3[4];
#pragma unroll
    for (int j = 0; j < 4; ++j) {
        const float x = x0 + (float)j;
        xw1[j] = x;
        xw2[j] = x * x;
        xw3[j] = x * x * x;
    }
    const float ybase = (float)(tid >> 5);   // y = ybase + 8*i

    float acc[10];
#pragma unroll
    for (int i = 0; i < 10; ++i) acc[i] = 0.0f;

#pragma unroll
    for (int i = 0; i < 16; ++i) {
        const f4v v = img[tid + i * 256];
        const float y  = ybase + (float)(i << 3);
        const float y2 = y * y;
        const float y3 = y2 * y;
        // Fixed-x dot products over the 4 pixels.
        float s0 = v.x + v.y + v.z + v.w;
        float s1 = v.x * xw1[0] + v.y * xw1[1] + v.z * xw1[2] + v.w * xw1[3];
        float s2 = v.x * xw2[0] + v.y * xw2[1] + v.z * xw2[2] + v.w * xw2[3];
        float s3 = v.x * xw3[0] + v.y * xw3[1] + v.z * xw3[2] + v.w * xw3[3];
        acc[0] += s0;        // m00
        acc[1] += s1;        // m10
        acc[2] += s0 * y;    // m01
        acc[3] += s2;        // m20
        acc[4] += s1 * y;    // m11
        acc[5] += s0 * y2;   // m02
        acc[6] += s3;        // m30
        acc[7] += s2 * y;    // m21
        acc[8] += s1 * y2;   // m12
        acc[9] += s0 * y3;   // m03
    }

    // Intra-wave 64-lane shfl_down tree reduce.
#pragma unroll
    for (int off = 32; off > 0; off >>= 1) {
#pragma unroll
        for (int i = 0; i < 10; ++i)
            acc[i] += __shfl_down(acc[i], off, 64);
    }

    // Cross-wave reduce through LDS (4 waves x 10 floats).
    __shared__ float red[4][10];
    const int wave = tid >> 6;
    const int lane = tid & 63;
    if (lane == 0) {
#pragma unroll
        for (int i = 0; i < 10; ++i) red[wave][i] = acc[i];
    }
    __syncthreads();
    if (tid < 10) {
        const float s = red[0][tid] + red[1][tid] + red[2][tid] + red[3][tid];
        out[(size_t)b * 10 + tid] = s;
    }
}

extern "C" void kernel_launch(void* const* d_in, const int* in_sizes, int n_in,
                              void* d_out, int out_size, void* d_ws, size_t ws_size,
                              hipStream_t stream)
{
    const float* in = (const float*)d_in[0];
    float* out = (float*)d_out;
    const int n_imgs = in_sizes[0] / IMG_ELEMS;   // 4096
    RawMoments_kernel<<<n_imgs, 256, 0, stream>>>(in, out);
}